// Round 13
// baseline (561.274 us; speedup 1.0000x reference)
//
#include <hip/hip_runtime.h>
#include <hip/hip_bf16.h>
#include <math.h>

// Problem dims
#define S_LEN   4096
#define B_SZ    2
#define E_DIM   1024
#define H_HEADS 8
#define R_ROUNDS 2
#define C_CHUNK 64
#define D_HEAD  128
#define NC_CHUNKS 64
#define QV_STRIDE 2048              // q (1024) | v (1024) per row
#define SCALE_F 0.08838834764831845f
#define NEG_F (-1e9f)
#define NEG_SELF_F (-1e5f)

typedef __attribute__((ext_vector_type(8))) short short8;
typedef __attribute__((ext_vector_type(4))) float f32x4;

// fp32 -> bf16 (RNE) bit pattern
__device__ inline unsigned bfr(float x){
  unsigned u = __float_as_uint(x);
  return (u + 0x7fffu + ((u >> 16) & 1u)) >> 16;
}
__device__ inline unsigned bpack2(float a, float b){ return bfr(a) | (bfr(b) << 16); }
__device__ inline float bf2f(unsigned short v){ return __uint_as_float((unsigned)v << 16); }

// async global->LDS 16B copy (wave-uniform LDS base + lane*16 semantics)
__device__ inline void gl_lds16(const void* g, void* l){
  __builtin_amdgcn_global_load_lds((const __attribute__((address_space(1))) unsigned*)g,
                                   (__attribute__((address_space(3))) unsigned*)l, 16, 0, 0);
}

// LDS column remap for 128-wide fp32 GEMM tiles
__device__ inline int sm_col(int c){ return ((c & 4) << 4) | ((c >> 3) << 2) | (c & 3); }

// ---------- fp32 tiled GEMM (q projection ONLY) — R2-best, 219.5us ----------
// Single fp32 FMA chain per output, k ascending — mirrors CPU sgemm so q
// feeding the discrete hash argmax matches reference rounding.
// CHAIN ORDER IS SACRED. PARKED at the LDS-return-path wall (66% VALUBusy);
// R9-R13 alternatives all regressed. Emulated-fp32-via-MFMA rejected:
// reassociation noise ~2e-6 risks hash argmax flips AND absmax sits exactly
// at 0.0078125 (zero margin).
__device__ inline void pref4(float4 (&va)[4], float4 (&vw)[4],
                             const float* __restrict__ Ap, const float* __restrict__ Wp,
                             int kt, int K){
  #pragma unroll
  for (int ii=0; ii<4; ii++){
    va[ii] = *(const float4*)(Ap + kt + (size_t)ii*32*K);
    vw[ii] = *(const float4*)(Wp + kt + (size_t)ii*32*K);
  }
}

__device__ inline void stage4(float (*a_s)[128], float (*w_s)[128],
                              const float4 (&va)[4], const float4 (&vw)[4],
                              int srow, int scol, int swz){
  #pragma unroll
  for (int ii=0; ii<4; ii++){
    int cp = sm_col(srow + ii*32) ^ swz;   // swz = (t&7)<<2 == f(scol+j) for j=0..3
    a_s[scol+0][cp]=va[ii].x; a_s[scol+1][cp]=va[ii].y; a_s[scol+2][cp]=va[ii].z; a_s[scol+3][cp]=va[ii].w;
    w_s[scol+0][cp]=vw[ii].x; w_s[scol+1][cp]=vw[ii].y; w_s[scol+2][cp]=vw[ii].z; w_s[scol+3][cp]=vw[ii].w;
  }
}

__device__ inline void comp32(const float (*a_s)[128], const float (*w_s)[128],
                              float (&acc)[8][8], int tx, int ty){
  #pragma unroll 4
  for (int kk=0; kk<32; kk++){
    int fk = ((kk>>2)&7)<<2;               // must match store-side swizzle
    int ca = (ty*4) ^ fk;
    int cw = (tx*4) ^ fk;
    float4 a0  = *(const float4*)&a_s[kk][ca];
    float4 a1  = *(const float4*)&a_s[kk][64+ca];
    float4 w0v = *(const float4*)&w_s[kk][cw];
    float4 w1v = *(const float4*)&w_s[kk][64+cw];
    float am[8] = {a0.x,a0.y,a0.z,a0.w,a1.x,a1.y,a1.z,a1.w};
    float wm[8] = {w0v.x,w0v.y,w0v.z,w0v.w,w1v.x,w1v.y,w1v.z,w1v.w};
    #pragma unroll
    for (int i=0;i<8;i++)
      #pragma unroll
      for (int j=0;j<8;j++)
        acc[i][j] = fmaf(am[i], wm[j], acc[i][j]);
  }
}

__global__ __launch_bounds__(256) void gemm_f32_kernel(
    const float* __restrict__ A, const float* __restrict__ W, const float* __restrict__ bia,
    float* __restrict__ Cout, int N, int K, int ldc)
{
  __shared__ __align__(16) float a_s[2][32][128];
  __shared__ __align__(16) float w_s[2][32][128];
  const int t  = threadIdx.x;
  const int n0 = blockIdx.x * 128;
  const int m0 = blockIdx.y * 128;
  const int tx = t & 15, ty = t >> 4;

  float acc[8][8];
  #pragma unroll
  for (int i=0;i<8;i++)
    #pragma unroll
    for (int j=0;j<8;j++) acc[i][j]=0.f;

  const int srow = t >> 3;
  const int scol = (t & 7) * 4;
  const int swz  = (t & 7) << 2;

  const float* Ap = A + (size_t)(m0 + srow)*K + scol;
  const float* Wp = W + (size_t)(n0 + srow)*K + scol;

  float4 va[4], vw[4];
  pref4(va, vw, Ap, Wp, 0, K);
  stage4(a_s[0], w_s[0], va, vw, srow, scol, swz);
  pref4(va, vw, Ap, Wp, 32, K);
  __syncthreads();

  const int NPH = K >> 5;                  // 32 phases of BK=32
  for (int p = 0; p < NPH; ++p){
    const float (*ac)[128] = a_s[p & 1];
    const float (*wc)[128] = w_s[p & 1];
    if (p + 1 < NPH){
      stage4(a_s[(p+1)&1], w_s[(p+1)&1], va, vw, srow, scol, swz);
      if (p + 2 < NPH) pref4(va, vw, Ap, Wp, (p+2)*32, K);
    }
    comp32(ac, wc, acc, tx, ty);
    __syncthreads();
  }

  float bias[8];
  #pragma unroll
  for (int j=0;j<8;j++) bias[j] = bia[n0 + tx*8 + j];
  #pragma unroll
  for (int i=0;i<8;i++){
    int row = m0 + ty*8 + i;
    float4 o0 = {acc[i][0]+bias[0], acc[i][1]+bias[1], acc[i][2]+bias[2], acc[i][3]+bias[3]};
    float4 o1 = {acc[i][4]+bias[4], acc[i][5]+bias[5], acc[i][6]+bias[6], acc[i][7]+bias[7]};
    *(float4*)(Cout + (size_t)row*ldc + n0 + tx*8)     = o0;
    *(float4*)(Cout + (size_t)row*ldc + n0 + tx*8 + 4) = o1;
  }
}

// ---------- elementwise f32 -> bf16 (RNE, identical bits to bpack2) ----------
__global__ __launch_bounds__(256) void cvt_bf16_kernel(const float* __restrict__ src,
                                                       unsigned short* __restrict__ dst,
                                                       int n8)
{
  int i = blockIdx.x*256 + threadIdx.x;
  if (i < n8){
    const float4 f0 = *(const float4*)(src + (size_t)i*8);
    const float4 f1 = *(const float4*)(src + (size_t)i*8 + 4);
    uint4 u = { bpack2(f0.x,f0.y), bpack2(f0.z,f0.w), bpack2(f1.x,f1.y), bpack2(f1.z,f1.w) };
    *(uint4*)(dst + (size_t)i*8) = u;
  }
}

// ---------- v-proj: pure-bf16 GEMM with global_load_lds staging (R15-validated) ----------
__global__ __launch_bounds__(256) void gemm_bf16gl_kernel(
    const unsigned short* __restrict__ A16, const unsigned short* __restrict__ W16,
    const float* __restrict__ bias, float* __restrict__ C,
    int K, int ldc)
{
  __shared__ __align__(16) unsigned short a_sh[128*64];
  __shared__ __align__(16) unsigned short w_sh[128*64];
  const int t = threadIdx.x;
  const int m0 = blockIdx.y * 128, n0 = blockIdx.x * 128;
  const int lane = t & 63, wid = t >> 6;
  const int mw = (wid >> 1) * 64, nw = (wid & 1) * 64;
  const int lr = lane & 15, lg = lane >> 4;

  f32x4 acc[4][4];
  #pragma unroll
  for (int i=0;i<4;i++)
    #pragma unroll
    for (int j=0;j<4;j++) acc[i][j] = (f32x4){0.f,0.f,0.f,0.f};

  const int srow0 = t >> 3;
  const int swzr  = srow0 & 7;
  const int gc8   = (t & 7) ^ swzr;
  const int rsw   = lr & 7;

  for (int kt = 0; kt < K; kt += 64){
    __syncthreads();
    #pragma unroll
    for (int i=0;i<4;i++){
      int row = srow0 + i*32;
      gl_lds16(A16 + (size_t)(m0+row)*K + kt + gc8*8, &a_sh[((size_t)i*256 + t)*8]);
      gl_lds16(W16 + (size_t)(n0+row)*K + kt + gc8*8, &w_sh[((size_t)i*256 + t)*8]);
    }
    __syncthreads();
    #pragma unroll
    for (int ks = 0; ks < 64; ks += 32){
      const int cg = (ks >> 3) + lg;
      const int sl = (cg ^ rsw) * 8;
      short8 af[4], bw[4];
      #pragma unroll
      for (int i=0;i<4;i++) af[i] = *(const short8*)&a_sh[(mw + i*16 + lr)*64 + sl];
      #pragma unroll
      for (int j=0;j<4;j++) bw[j] = *(const short8*)&w_sh[(nw + j*16 + lr)*64 + sl];
      #pragma unroll
      for (int i=0;i<4;i++)
        #pragma unroll
        for (int j=0;j<4;j++)
          acc[i][j] = __builtin_amdgcn_mfma_f32_16x16x32_bf16(af[i], bw[j], acc[i][j], 0, 0, 0);
    }
  }
  #pragma unroll
  for (int j=0;j<4;j++){
    int col = n0 + nw + j*16 + lr;
    float bs = bias[col];
    #pragma unroll
    for (int i=0;i<4;i++){
      int rbase = m0 + mw + i*16 + lg*4;
      #pragma unroll
      for (int r=0;r<4;r++)
        C[(size_t)(rbase+r)*ldc + col] = acc[i][j][r] + bs;
    }
  }
}

// ---------- out-proj with fused round-combine in A-staging (R14-validated) ----------
#define BST 72
__global__ __launch_bounds__(256) void gemm_out_kernel(
    const unsigned short* __restrict__ o_r16, const float* __restrict__ lse,
    const float* __restrict__ W, const float* __restrict__ bias,
    float* __restrict__ C)
{
  const int K = 1024, ldc = 1024;
  __shared__ unsigned short a_sh[128*BST];
  __shared__ unsigned short w_sh[128*BST];
  const int t = threadIdx.x;
  const int m0 = blockIdx.y * 128, n0 = blockIdx.x * 128;
  const int lane = t & 63, wid = t >> 6;
  const int mw = (wid >> 1) * 64, nw = (wid & 1) * 64;
  const int lr = lane & 15, lg = lane >> 4;

  f32x4 acc[4][4];
  #pragma unroll
  for (int i=0;i<4;i++)
    #pragma unroll
    for (int j=0;j<4;j++) acc[i][j] = (f32x4){0.f,0.f,0.f,0.f};

  const int srow = t >> 3;
  const int scol = (t & 7) * 8;

  for (int kt = 0; kt < K; kt += 64){
    __syncthreads();
    const int h = kt >> 7;
    const int dbase = (kt & 64) + scol;        // column within head, 0..120
    #pragma unroll
    for (int ii = 0; ii < 4; ii++){
      int row = srow + ii*32;
      int grow = m0 + row;
      int s = grow >> 1, b = grow & 1;
      size_t i0 = (size_t)((b*2 + 0)*8 + h)*S_LEN + s;
      size_t i1 = (size_t)((b*2 + 1)*8 + h)*S_LEN + s;
      float l0 = lse[i0], l1 = lse[i1];
      float mm = fmaxf(l0,l1);
      float w0 = expf(l0-mm), w1 = expf(l1-mm);
      float inv = 1.0f/(w0+w1);
      w0*=inv; w1*=inv;
      const unsigned short* p0 = o_r16 + i0*128 + dbase;
      const unsigned short* p1 = o_r16 + i1*128 + dbase;
      uint4 u0 = *(const uint4*)p0;
      uint4 u1 = *(const uint4*)p1;
      float f[8];
      #pragma unroll
      for (int j=0;j<4;j++){
        unsigned av = ((const unsigned*)&u0)[j];
        unsigned cv = ((const unsigned*)&u1)[j];
        f[2*j]   = w0*bf2f((unsigned short)(av & 0xffff)) + w1*bf2f((unsigned short)(cv & 0xffff));
        f[2*j+1] = w0*bf2f((unsigned short)(av >> 16))    + w1*bf2f((unsigned short)(cv >> 16));
      }
      uint4 ua = { bpack2(f[0],f[1]), bpack2(f[2],f[3]), bpack2(f[4],f[5]), bpack2(f[6],f[7]) };
      *(uint4*)&a_sh[row*BST + scol] = ua;
      const float4 g0 = *(const float4*)(W + (size_t)(n0+row)*K + kt + scol);
      const float4 g1 = *(const float4*)(W + (size_t)(n0+row)*K + kt + scol + 4);
      uint4 uw = { bpack2(g0.x,g0.y), bpack2(g0.z,g0.w), bpack2(g1.x,g1.y), bpack2(g1.z,g1.w) };
      *(uint4*)&w_sh[row*BST + scol] = uw;
    }
    __syncthreads();
    #pragma unroll
    for (int ks = 0; ks < 64; ks += 32){
      short8 af[4], bw[4];
      #pragma unroll
      for (int i=0;i<4;i++) af[i] = *(const short8*)&a_sh[(mw + i*16 + lr)*BST + ks + lg*8];
      #pragma unroll
      for (int j=0;j<4;j++) bw[j] = *(const short8*)&w_sh[(nw + j*16 + lr)*BST + ks + lg*8];
      #pragma unroll
      for (int i=0;i<4;i++)
        #pragma unroll
        for (int j=0;j<4;j++)
          acc[i][j] = __builtin_amdgcn_mfma_f32_16x16x32_bf16(af[i], bw[j], acc[i][j], 0, 0, 0);
    }
  }
  #pragma unroll
  for (int j=0;j<4;j++){
    int col = n0 + nw + j*16 + lr;
    float bs = bias[col];
    #pragma unroll
    for (int i=0;i<4;i++){
      int rbase = m0 + mw + i*16 + lg*4;
      #pragma unroll
      for (int r=0;r<4;r++)
        C[(size_t)(rbase+r)*ldc + col] = acc[i][j][r] + bs;
    }
  }
}

// ---------- per-row norm over E ----------
__global__ __launch_bounds__(256) void invnorm_kernel(const float* __restrict__ qv,
                                                      float* __restrict__ invn,
                                                      float* __restrict__ nrm)
{
  int row = blockIdx.x;
  int t = threadIdx.x;
  float4 v = *(const float4*)(qv + (size_t)row*QV_STRIDE + t*4);
  float ss = v.x*v.x + v.y*v.y + v.z*v.z + v.w*v.w;
  #pragma unroll
  for (int off=32; off; off>>=1) ss += __shfl_down(ss, off);
  __shared__ float part[4];
  if ((t & 63)==0) part[t>>6] = ss;
  __syncthreads();
  if (t==0){
    float n = sqrtf(part[0]+part[1]+part[2]+part[3]);
    nrm[row]  = n;
    invn[row] = 1.0f/n;
  }
}

// ---------- fp32 hash path, reference-order mimicry (R5 pass; DO NOT TOUCH) ----------
__global__ __launch_bounds__(256) void hash32_kernel(
    const float* __restrict__ qv, const float* __restrict__ nrm,
    const float* __restrict__ hw, int* __restrict__ hashes)
{
  int idx = blockIdx.x*256 + threadIdx.x;
  int s = idx & (S_LEN-1);
  int h = (idx >> 12) & 7;
  int r = (idx >> 15) & 1;
  int b = idx >> 16;
  const float* qr = qv + (size_t)(s*B_SZ + b)*QV_STRIDE + h*D_HEAD;
  const float  n  = nrm[s*B_SZ + b];
  const float* wp = hw + (size_t)(r*H_HEADS + h)*D_HEAD*8;
  float lin[8];
  #pragma unroll
  for (int m=0;m<8;m++) lin[m]=0.f;
  for (int d=0; d<D_HEAD; d++){
    float kd = qr[d] / n;
    #pragma unroll
    for (int m=0;m<8;m++) lin[m] = fmaf(kd, wp[d*8+m], lin[m]);
  }
  float best = lin[0]; int bi = 0;
  #pragma unroll
  for (int m=1;m<8;m++) if (lin[m] > best){ best=lin[m]; bi=m; }
  #pragma unroll
  for (int m=0;m<8;m++) if (-lin[m] > best){ best=-lin[m]; bi=8+m; }
  hashes[idx] = bi;
}

// ---------- stable counting sort by bucket, per (b,r,h) ----------
__global__ __launch_bounds__(256) void sort_kernel(const int* __restrict__ hashes,
                                                   int* __restrict__ sidx,
                                                   unsigned short* __restrict__ hs_pack)
{
  __shared__ unsigned char bucket_s[S_LEN];
  __shared__ int counts[16][257];
  __shared__ int bbase[16];
  int t = threadIdx.x;
  size_t base = (size_t)blockIdx.x * S_LEN;
  for (int e=0;e<16;e++) bucket_s[t + e*256] = (unsigned char)hashes[base + t + e*256];
  #pragma unroll
  for (int u=0;u<16;u++) counts[u][t]=0;
  if (t<16) counts[t][256]=0;
  __syncthreads();
  int s0 = t*16;
  for (int e=0;e<16;e++){ int u = bucket_s[s0+e]; counts[u][t]++; }
  __syncthreads();
  if (t < 16){
    int run=0;
    for (int tt=0; tt<256; tt++){ int c = counts[t][tt]; counts[t][tt]=run; run+=c; }
    counts[t][256]=run;
  }
  __syncthreads();
  if (t==0){
    int run=0;
    for (int u=0;u<16;u++){ bbase[u]=run; run += counts[u][256]; }
  }
  __syncthreads();
  for (int e=0;e<16;e++){
    int s = s0+e; int u = bucket_s[s];
    int pos = bbase[u] + counts[u][t]; counts[u][t]++;
    sidx[base+pos] = s;
    hs_pack[base+pos] = (unsigned short)(s | (u<<12));
  }
}

// ---------- gather: sorted bf16 K-hat rows + transposed V ----------
#define GST 136
__global__ __launch_bounds__(256) void gather_kernel(
    const float* __restrict__ qv, const float* __restrict__ invn,
    const int* __restrict__ sidx,
    unsigned short* __restrict__ ksort, unsigned short* __restrict__ vsortT)
{
  __shared__ int tok_s[256];
  __shared__ float sc_s[256];
  __shared__ unsigned short v_sub[64*GST];
  const int t = threadIdx.x;
  const int brh = blockIdx.x >> 4, pc = blockIdx.x & 15;
  const int b = brh >> 4;
  const int h = brh & 7;
  const size_t base_s = (size_t)brh * S_LEN;
  const int pos0 = pc * 256;
  {
    int tok = sidx[base_s + pos0 + t];
    tok_s[t] = tok;
    sc_s[t] = invn[tok*B_SZ + b];
  }
  __syncthreads();
  // ksort: coalesced row-major bf16
  #pragma unroll 4
  for (int i=0;i<16;i++){
    int slot = i*256 + t;
    int pos = slot >> 4, g = slot & 15;
    int tok = tok_s[pos]; float sc = sc_s[pos];
    const float* src = qv + ((size_t)tok*B_SZ + b)*QV_STRIDE + h*D_HEAD + g*8;
    float4 f0 = *(const float4*)src, f1 = *(const float4*)(src+4);
    uint4 u = { bpack2(f0.x*sc, f0.y*sc), bpack2(f0.z*sc, f0.w*sc),
                bpack2(f1.x*sc, f1.y*sc), bpack2(f1.z*sc, f1.w*sc) };
    *(uint4*)&ksort[(base_s + pos0 + pos)*128 + g*8] = u;
  }
  // vsortT: 4 sub-tiles of 64 pos, LDS transpose
  for (int sub=0; sub<4; sub++){
    __syncthreads();
    #pragma unroll
    for (int i=0;i<4;i++){
      int slot = i*256 + t;
      int pr = slot >> 4, g = slot & 15;
      int tok = tok_s[sub*64 + pr];
      const float* src = qv + ((size_t)tok*B_SZ + b)*QV_STRIDE + 1024 + h*D_HEAD + g*8;
      float4 f0 = *(const float4*)src, f1 = *(const float4*)(src+4);
      uint4 u = { bpack2(f0.x,f0.y), bpack2(f0.z,f0.w), bpack2(f1.x,f1.y), bpack2(f1.z,f1.w) };
      *(uint4*)&v_sub[pr*GST + g*8] = u;
    }
    __syncthreads();
    #pragma unroll
    for (int i=0;i<8;i++){
      int oslot = i*256 + t;             // 2048 = 128 d x 16 pos-groups
      int d = oslot >> 4, p4 = (oslot & 15)*4;
      unsigned a0 = v_sub[(p4+0)*GST + d];
      unsigned a1 = v_sub[(p4+1)*GST + d];
      unsigned a2 = v_sub[(p4+2)*GST + d];
      unsigned a3 = v_sub[(p4+3)*GST + d];
      uint2 o = { a0 | (a1<<16), a2 | (a3<<16) };
      *(uint2*)&vsortT[(size_t)brh*524288 + (size_t)d*4096 + pos0 + sub*64 + p4] = o;
    }
  }
}

// ---------- MFMA chunked LSH attention ----------
// Reference quirk (silent broadcast): for query at sorted position p=n*64+c,
// scores/values use win(n), but BOTH masks compare vs win(c).
// R17: T14 async-STAGE split — window loads issue into regs ONE WINDOW
// AHEAD (K w0 under prologue, K w+1 under QK MFMAs, V w0 under softmax,
// V w+1 under PV MFMAs). Same ops, same barriers, identical arithmetic.
#define KST 136
#define VST 72
#define PST 200
__device__ inline int swzg(int row, int g){ return (g ^ (row & 7)) << 3; }

__global__ __launch_bounds__(256) void attn_mfma_kernel(
    const unsigned short* __restrict__ ksort, const unsigned short* __restrict__ vsortT,
    const float* __restrict__ nrm, const unsigned short* __restrict__ hs_pack,
    unsigned short* __restrict__ o_r16, float* __restrict__ lse_g)
{
  __shared__ unsigned short kv_un[128*VST];          // 9216 u16: K chunk (64x136) or V^T chunk (128x72)
  __shared__ unsigned short p_sh[64*PST];
  __shared__ __align__(16) unsigned short pack_s[S_LEN];
  __shared__ float srow_s[64];

  const int t = threadIdx.x;
  const int bid = blockIdx.x;
  const int nc = bid & 63;
  const int brh = bid >> 6;
  const int b = brh >> 4;
  const size_t base_s = (size_t)brh * S_LEN;

  // T14 prologue: issue K loads for first window (w=1) — hide under pack_s phase
  uint4 stg[4];
  {
    int cw = (nc + 1 + 63) & 63;           // worder[0] = 1
    #pragma unroll
    for (int i=0;i<4;i++){
      int slot = i*256 + t;
      int row = slot >> 4, g = slot & 15;
      stg[i] = *(const uint4*)&ksort[(base_s + cw*64 + row)*128 + g*8];
    }
  }

  {
    const uint4* src = (const uint4*)(hs_pack + base_s);
    uint4* dst = (uint4*)pack_s;
    dst[t]       = src[t];
    dst[256 + t] = src[256 + t];
  }
  __syncthreads();
  if (t < 64){
    int tok = pack_s[nc*64 + t] & 0xfff;
    srow_s[t] = SCALE_F * nrm[tok*B_SZ + b];
  }

  const int lane = t & 63, wid = t >> 6;
  const int mw = wid * 16;                 // wave's 16 query rows
  const int lr = lane & 15, lg = lane >> 4;

  f32x4 acc[12];
  #pragma unroll
  for (int i=0;i<12;i++) acc[i] = (f32x4){0.f,0.f,0.f,0.f};
  short8 aq[4];

  // ---- QK^T: window chunks, w=1 first (supplies Q fragments) ----
  const int worder[3] = {1, 0, 2};
  #pragma unroll
  for (int wi=0; wi<3; wi++){
    int w = worder[wi];
    __syncthreads();                       // kv_un free; also covers srow_s on first iter
    #pragma unroll
    for (int i=0;i<4;i++){
      int slot = i*256 + t;
      int row = slot >> 4, g = slot & 15;
      *(uint4*)&kv_un[row*KST + swzg(row, g)] = stg[i];
    }
    if (wi < 2){                           // issue next K window — hides under MFMAs
      int cw = (nc + worder[wi+1] + 63) & 63;
      #pragma unroll
      for (int i=0;i<4;i++){
        int slot = i*256 + t;
        int row = slot >> 4, g = slot & 15;
        stg[i] = *(const uint4*)&ksort[(base_s + cw*64 + row)*128 + g*8];
      }
    }
    __syncthreads();
    if (wi==0){
      #pragma unroll
      for (int ks=0; ks<4; ks++)
        aq[ks] = *(const short8*)&kv_un[(mw+lr)*KST + swzg(mw+lr, ks*4+lg)];
    }
    #pragma unroll
    for (int ks=0; ks<4; ks++){
      #pragma unroll
      for (int k4=0; k4<4; k4++){
        short8 bk = *(const short8*)&kv_un[(k4*16+lr)*KST + swzg(k4*16+lr, ks*4+lg)];
        acc[w*4+k4] = __builtin_amdgcn_mfma_f32_16x16x32_bf16(aq[ks], bk, acc[w*4+k4], 0,0,0);
      }
    }
  }

  // T14: issue V w=0 loads — hide under the long softmax
  {
    int cw = (nc + 63) & 63;
    #pragma unroll
    for (int i=0;i<4;i++){
      int slot = i*256 + t;
      int d = slot >> 3, kg = slot & 7;
      stg[i] = *(const uint4*)&vsortT[(size_t)brh*524288 + (size_t)d*4096 + cw*64 + kg*8];
    }
  }

  // ---- scale + masks + softmax (C-layout: col=lr, rows mw+lg*4+r) ----
  unsigned pq[4]; float sr[4]; int c_[4]; float linv[4];
  #pragma unroll
  for (int r=0;r<4;r++){
    c_[r] = mw + lg*4 + r;
    pq[r] = pack_s[nc*64 + c_[r]];
    sr[r] = srow_s[c_[r]];
  }
  #pragma unroll
  for (int ti=0; ti<12; ti++){
    int w = ti >> 2, k4 = ti & 3;
    #pragma unroll
    for (int r=0;r<4;r++){
      int mc = (c_[r] + w + 63) & 63;
      unsigned e = pack_s[mc*64 + k4*16 + lr];
      float s = acc[ti][r] * sr[r];
      s = ((e>>12) == (pq[r]>>12)) ? s : NEG_F;
      if ((e & 0xfffu) == (pq[r] & 0xfffu)) s = NEG_SELF_F;
      acc[ti][r] = s;
    }
  }
  #pragma unroll
  for (int r=0;r<4;r++){
    float m = acc[0][r];
    #pragma unroll
    for (int ti=1; ti<12; ti++) m = fmaxf(m, acc[ti][r]);
    #pragma unroll
    for (int off=1; off<16; off<<=1) m = fmaxf(m, __shfl_xor(m, off));
    float l = 0.f;
    #pragma unroll
    for (int ti=0; ti<12; ti++){
      float p = __expf(acc[ti][r] - m);
      l += p;
      int wpos = (ti>>2)*64 + (ti&3)*16 + lr;
      p_sh[c_[r]*PST + (((wpos>>3) ^ (c_[r]&7))<<3) + (wpos&7)] = (unsigned short)bfr(p);
    }
    #pragma unroll
    for (int off=1; off<16; off<<=1) l += __shfl_xor(l, off);
    linv[r] = 1.0f / l;
    if (lr == 0) lse_g[base_s + (pq[r] & 0xfffu)] = m + logf(l);
  }

  // ---- PV ----
  f32x4 oacc[8];
  #pragma unroll
  for (int i=0;i<8;i++) oacc[i] = (f32x4){0.f,0.f,0.f,0.f};
  for (int w=0; w<3; w++){
    __syncthreads();                       // kv_un free (p_sh is intra-wave)
    #pragma unroll
    for (int i=0;i<4;i++){
      int slot = i*256 + t;                // 1024 = 128 d x 8 key-groups
      int d = slot >> 3, kg = slot & 7;
      *(uint4*)&kv_un[d*VST + swzg(d, kg)] = stg[i];
    }
    if (w < 2){                            // issue next V window — hides under PV MFMAs
      int cw = (nc + w + 64) & 63;         // (nc + (w+1) + 63) & 63
      #pragma unroll
      for (int i=0;i<4;i++){
        int slot = i*256 + t;
        int d = slot >> 3, kg = slot & 7;
        stg[i] = *(const uint4*)&vsortT[(size_t)brh*524288 + (size_t)d*4096 + cw*64 + kg*8];
      }
    }
    __syncthreads();
    short8 ap[2];
    #pragma unroll
    for (int ks=0; ks<2; ks++){
      int g = w*8 + ks*4 + lg;
      ap[ks] = *(const short8*)&p_sh[(mw+lr)*PST + ((g ^ ((mw+lr)&7))<<3)];
    }
    #pragma unroll
    for (int ks=0; ks<2; ks++)
      #pragma unroll
      for (int dt=0; dt<8; dt++){
        short8 bv = *(const short8*)&kv_un[(dt*16+lr)*VST + swzg(dt*16+lr, ks*4+lg)];
        oacc[dt] = __builtin_amdgcn_mfma_f32_16x16x32_bf16(ap[ks], bv, oacc[dt], 0,0,0);
      }
  }

  // ---- epilogue: bf16 scatter by token ----
  #pragma unroll
  for (int r=0;r<4;r++){
    int tok = pq[r] & 0xfff;
    size_t ob = (base_s + tok) * 128;
    #pragma unroll
    for (int dt=0; dt<8; dt++)
      o_r16[ob + dt*16 + lr] = (unsigned short)bfr(oacc[dt][r] * linv[r]);
  }
}

// ---------- launch ----------
extern "C" void kernel_launch(void* const* d_in, const int* in_sizes, int n_in,
                              void* d_out, int out_size, void* d_ws, size_t ws_size,
                              hipStream_t stream)
{
  (void)in_sizes; (void)n_in; (void)out_size; (void)ws_size;
  const float* x  = (const float*)d_in[0];
  const float* wq = (const float*)d_in[1];
  const float* bq = (const float*)d_in[2];
  const float* wv = (const float*)d_in[3];
  const float* bv = (const float*)d_in[4];
  const float* wo = (const float*)d_in[5];
  const float* bo = (const float*)d_in[6];
  const float* hw = (const float*)d_in[7];
  float* out = (float*)d_out;

  float* ws    = (float*)d_ws;
  float* qv    = ws;                          // [8192][2048] q|v fp32
  float* invn  = ws + 16777216;               // [8192]
  float* nrm   = ws + 16785408;               // [8192]
  int*   hashes= (int*)(ws + 16793600);       // [B,R,H,S]
  int*   sidx  = (int*)(ws + 16924672);       // [B,R,H,S]
  float* lse   = ws + 17055744;               // [B,R,H,S]
  unsigned short* o_r16   = (unsigned short*)(ws + 17186816);  // [32][4096][128] bf16 (written at attn)
  unsigned short* x16     = (unsigned short*)(ws + 17186816);  // overlays o_r16 front 16MB (dead before attn)
  unsigned short* wv16    = (unsigned short*)(ws + 21381120);  // overlays o_r16 tail (dead before attn)
  unsigned short* ksort   = (unsigned short*)(ws + 25575424);  // [32][4096][128] bf16
  unsigned short* vsortT  = (unsigned short*)(ws + 33964032);  // [32][128][4096] bf16
  unsigned short* hs_pack = (unsigned short*)(ws + 42352640);  // [B,R,H,S] packed

  cvt_bf16_kernel<<<dim3(4096), 256, 0, stream>>>(x,  x16,  1048576);   // 8192*1024/8
  cvt_bf16_kernel<<<dim3(512),  256, 0, stream>>>(wv, wv16, 131072);    // 1024*1024/8
  gemm_f32_kernel<<<dim3(8,64), 256, 0, stream>>>(x, wq, bq, qv, 1024, 1024, QV_STRIDE);
  gemm_bf16gl_kernel<<<dim3(8,64), 256, 0, stream>>>(x16, wv16, bv, qv + 1024, 1024, QV_STRIDE);
  invnorm_kernel<<<dim3(8192), 256, 0, stream>>>(qv, invn, nrm);
  hash32_kernel<<<dim3(512), 256, 0, stream>>>(qv, nrm, hw, hashes);
  sort_kernel<<<dim3(32), 256, 0, stream>>>(hashes, sidx, hs_pack);
  gather_kernel<<<dim3(512), 256, 0, stream>>>(qv, invn, sidx, ksort, vsortT);
  attn_mfma_kernel<<<dim3(2048), 256, 0, stream>>>(ksort, vsortT, nrm, hs_pack, o_r16, lse);
  gemm_out_kernel<<<dim3(8,64), 256, 0, stream>>>(o_r16, lse, wo, bo, out);
}

// Round 15
// 503.282 us; speedup vs baseline: 1.1152x; 1.1152x over previous
//
#include <hip/hip_runtime.h>
#include <hip/hip_bf16.h>
#include <math.h>

// Problem dims
#define S_LEN   4096
#define B_SZ    2
#define E_DIM   1024
#define H_HEADS 8
#define R_ROUNDS 2
#define C_CHUNK 64
#define D_HEAD  128
#define NC_CHUNKS 64
#define SCALE_F 0.08838834764831845f
#define NEG_F (-1e9f)
#define NEG_SELF_F (-1e5f)

typedef __attribute__((ext_vector_type(8))) short short8;
typedef __attribute__((ext_vector_type(4))) float f32x4;

// fp32 -> bf16 (RNE) bit pattern
__device__ inline unsigned bfr(float x){
  unsigned u = __float_as_uint(x);
  return (u + 0x7fffu + ((u >> 16) & 1u)) >> 16;
}
__device__ inline unsigned bpack2(float a, float b){ return bfr(a) | (bfr(b) << 16); }
__device__ inline float bf2f(unsigned short v){ return __uint_as_float((unsigned)v << 16); }

// async global->LDS 16B copy (wave-uniform LDS base + lane*16 semantics)
__device__ inline void gl_lds16(const void* g, void* l){
  __builtin_amdgcn_global_load_lds((const __attribute__((address_space(1))) unsigned*)g,
                                   (__attribute__((address_space(3))) unsigned*)l, 16, 0, 0);
}

// LDS column remap for 128-wide fp32 GEMM tiles
__device__ inline int sm_col(int c){ return ((c & 4) << 4) | ((c >> 3) << 2) | (c & 3); }

// ---------- fp32 tiled GEMM (q projection ONLY) — R2-best, 219.5us ----------
// Single fp32 FMA chain per output, k ascending — mirrors CPU sgemm so q
// feeding the discrete hash argmax matches reference rounding.
// CHAIN ORDER IS SACRED. PARKED at the LDS-return-path wall (66% VALUBusy);
// R9-R13 alternatives all regressed.
// (R14-round bench was an infra container failure; kernel audited clean —
// workspace ranges, OOB, barriers all verified. Resubmitted unchanged.)
__device__ inline void pref4(float4 (&va)[4], float4 (&vw)[4],
                             const float* __restrict__ Ap, const float* __restrict__ Wp,
                             int kt, int K){
  #pragma unroll
  for (int ii=0; ii<4; ii++){
    va[ii] = *(const float4*)(Ap + kt + (size_t)ii*32*K);
    vw[ii] = *(const float4*)(Wp + kt + (size_t)ii*32*K);
  }
}

__device__ inline void stage4(float (*a_s)[128], float (*w_s)[128],
                              const float4 (&va)[4], const float4 (&vw)[4],
                              int srow, int scol, int swz){
  #pragma unroll
  for (int ii=0; ii<4; ii++){
    int cp = sm_col(srow + ii*32) ^ swz;   // swz = (t&7)<<2 == f(scol+j) for j=0..3
    a_s[scol+0][cp]=va[ii].x; a_s[scol+1][cp]=va[ii].y; a_s[scol+2][cp]=va[ii].z; a_s[scol+3][cp]=va[ii].w;
    w_s[scol+0][cp]=vw[ii].x; w_s[scol+1][cp]=vw[ii].y; w_s[scol+2][cp]=vw[ii].z; w_s[scol+3][cp]=vw[ii].w;
  }
}

__device__ inline void comp32(const float (*a_s)[128], const float (*w_s)[128],
                              float (&acc)[8][8], int tx, int ty){
  #pragma unroll 4
  for (int kk=0; kk<32; kk++){
    int fk = ((kk>>2)&7)<<2;               // must match store-side swizzle
    int ca = (ty*4) ^ fk;
    int cw = (tx*4) ^ fk;
    float4 a0  = *(const float4*)&a_s[kk][ca];
    float4 a1  = *(const float4*)&a_s[kk][64+ca];
    float4 w0v = *(const float4*)&w_s[kk][cw];
    float4 w1v = *(const float4*)&w_s[kk][64+cw];
    float am[8] = {a0.x,a0.y,a0.z,a0.w,a1.x,a1.y,a1.z,a1.w};
    float wm[8] = {w0v.x,w0v.y,w0v.z,w0v.w,w1v.x,w1v.y,w1v.z,w1v.w};
    #pragma unroll
    for (int i=0;i<8;i++)
      #pragma unroll
      for (int j=0;j<8;j++)
        acc[i][j] = fmaf(am[i], wm[j], acc[i][j]);
  }
}

__global__ __launch_bounds__(256) void gemm_f32_kernel(
    const float* __restrict__ A, const float* __restrict__ W, const float* __restrict__ bia,
    float* __restrict__ Cout, int N, int K, int ldc)
{
  __shared__ __align__(16) float a_s[2][32][128];
  __shared__ __align__(16) float w_s[2][32][128];
  const int t  = threadIdx.x;
  const int n0 = blockIdx.x * 128;
  const int m0 = blockIdx.y * 128;
  const int tx = t & 15, ty = t >> 4;

  float acc[8][8];
  #pragma unroll
  for (int i=0;i<8;i++)
    #pragma unroll
    for (int j=0;j<8;j++) acc[i][j]=0.f;

  const int srow = t >> 3;
  const int scol = (t & 7) * 4;
  const int swz  = (t & 7) << 2;

  const float* Ap = A + (size_t)(m0 + srow)*K + scol;
  const float* Wp = W + (size_t)(n0 + srow)*K + scol;

  float4 va[4], vw[4];
  pref4(va, vw, Ap, Wp, 0, K);
  stage4(a_s[0], w_s[0], va, vw, srow, scol, swz);
  pref4(va, vw, Ap, Wp, 32, K);
  __syncthreads();

  const int NPH = K >> 5;                  // 32 phases of BK=32
  for (int p = 0; p < NPH; ++p){
    const float (*ac)[128] = a_s[p & 1];
    const float (*wc)[128] = w_s[p & 1];
    if (p + 1 < NPH){
      stage4(a_s[(p+1)&1], w_s[(p+1)&1], va, vw, srow, scol, swz);
      if (p + 2 < NPH) pref4(va, vw, Ap, Wp, (p+2)*32, K);
    }
    comp32(ac, wc, acc, tx, ty);
    __syncthreads();
  }

  float bias[8];
  #pragma unroll
  for (int j=0;j<8;j++) bias[j] = bia[n0 + tx*8 + j];
  #pragma unroll
  for (int i=0;i<8;i++){
    int row = m0 + ty*8 + i;
    float4 o0 = {acc[i][0]+bias[0], acc[i][1]+bias[1], acc[i][2]+bias[2], acc[i][3]+bias[3]};
    float4 o1 = {acc[i][4]+bias[4], acc[i][5]+bias[5], acc[i][6]+bias[6], acc[i][7]+bias[7]};
    *(float4*)(Cout + (size_t)row*ldc + n0 + tx*8)     = o0;
    *(float4*)(Cout + (size_t)row*ldc + n0 + tx*8 + 4) = o1;
  }
}

// ---------- elementwise f32 -> bf16 (RNE, identical bits to bpack2) ----------
__global__ __launch_bounds__(256) void cvt_bf16_kernel(const float* __restrict__ src,
                                                       unsigned short* __restrict__ dst,
                                                       int n8)
{
  int i = blockIdx.x*256 + threadIdx.x;
  if (i < n8){
    const float4 f0 = *(const float4*)(src + (size_t)i*8);
    const float4 f1 = *(const float4*)(src + (size_t)i*8 + 4);
    uint4 u = { bpack2(f0.x,f0.y), bpack2(f0.z,f0.w), bpack2(f1.x,f1.y), bpack2(f1.z,f1.w) };
    *(uint4*)(dst + (size_t)i*8) = u;
  }
}

// ---------- v-proj: bf16 GEMM, gl_lds staging, BF16 OUTPUT (R18) ----------
// Emits v directly as bf16 (bfr(acc+bias) — the exact bits gather's
// bpack2 produced from the fp32 value) -> halves v write + gather v read.
__global__ __launch_bounds__(256) void gemm_bf16v_kernel(
    const unsigned short* __restrict__ A16, const unsigned short* __restrict__ W16,
    const float* __restrict__ bias, unsigned short* __restrict__ C16,
    int K, int ldc)
{
  __shared__ __align__(16) unsigned short a_sh[128*64];
  __shared__ __align__(16) unsigned short w_sh[128*64];
  const int t = threadIdx.x;
  const int m0 = blockIdx.y * 128, n0 = blockIdx.x * 128;
  const int lane = t & 63, wid = t >> 6;
  const int mw = (wid >> 1) * 64, nw = (wid & 1) * 64;
  const int lr = lane & 15, lg = lane >> 4;

  f32x4 acc[4][4];
  #pragma unroll
  for (int i=0;i<4;i++)
    #pragma unroll
    for (int j=0;j<4;j++) acc[i][j] = (f32x4){0.f,0.f,0.f,0.f};

  const int srow0 = t >> 3;
  const int swzr  = srow0 & 7;
  const int gc8   = (t & 7) ^ swzr;
  const int rsw   = lr & 7;

  for (int kt = 0; kt < K; kt += 64){
    __syncthreads();
    #pragma unroll
    for (int i=0;i<4;i++){
      int row = srow0 + i*32;
      gl_lds16(A16 + (size_t)(m0+row)*K + kt + gc8*8, &a_sh[((size_t)i*256 + t)*8]);
      gl_lds16(W16 + (size_t)(n0+row)*K + kt + gc8*8, &w_sh[((size_t)i*256 + t)*8]);
    }
    __syncthreads();
    #pragma unroll
    for (int ks = 0; ks < 64; ks += 32){
      const int cg = (ks >> 3) + lg;
      const int sl = (cg ^ rsw) * 8;
      short8 af[4], bw[4];
      #pragma unroll
      for (int i=0;i<4;i++) af[i] = *(const short8*)&a_sh[(mw + i*16 + lr)*64 + sl];
      #pragma unroll
      for (int j=0;j<4;j++) bw[j] = *(const short8*)&w_sh[(nw + j*16 + lr)*64 + sl];
      #pragma unroll
      for (int i=0;i<4;i++)
        #pragma unroll
        for (int j=0;j<4;j++)
          acc[i][j] = __builtin_amdgcn_mfma_f32_16x16x32_bf16(af[i], bw[j], acc[i][j], 0, 0, 0);
    }
  }
  #pragma unroll
  for (int j=0;j<4;j++){
    int col = n0 + nw + j*16 + lr;
    float bs = bias[col];
    #pragma unroll
    for (int i=0;i<4;i++){
      int rbase = m0 + mw + i*16 + lg*4;
      #pragma unroll
      for (int r=0;r<4;r++)
        C16[(size_t)(rbase+r)*ldc + col] = (unsigned short)bfr(acc[i][j][r] + bs);
    }
  }
}

// ---------- out-proj with fused round-combine in A-staging (R14-validated) ----------
#define BST 72
__global__ __launch_bounds__(256) void gemm_out_kernel(
    const unsigned short* __restrict__ o_r16, const float* __restrict__ lse,
    const float* __restrict__ W, const float* __restrict__ bias,
    float* __restrict__ C)
{
  const int K = 1024, ldc = 1024;
  __shared__ unsigned short a_sh[128*BST];
  __shared__ unsigned short w_sh[128*BST];
  const int t = threadIdx.x;
  const int m0 = blockIdx.y * 128, n0 = blockIdx.x * 128;
  const int lane = t & 63, wid = t >> 6;
  const int mw = (wid >> 1) * 64, nw = (wid & 1) * 64;
  const int lr = lane & 15, lg = lane >> 4;

  f32x4 acc[4][4];
  #pragma unroll
  for (int i=0;i<4;i++)
    #pragma unroll
    for (int j=0;j<4;j++) acc[i][j] = (f32x4){0.f,0.f,0.f,0.f};

  const int srow = t >> 3;
  const int scol = (t & 7) * 8;

  for (int kt = 0; kt < K; kt += 64){
    __syncthreads();
    const int h = kt >> 7;
    const int dbase = (kt & 64) + scol;        // column within head, 0..120
    #pragma unroll
    for (int ii = 0; ii < 4; ii++){
      int row = srow + ii*32;
      int grow = m0 + row;
      int s = grow >> 1, b = grow & 1;
      size_t i0 = (size_t)((b*2 + 0)*8 + h)*S_LEN + s;
      size_t i1 = (size_t)((b*2 + 1)*8 + h)*S_LEN + s;
      float l0 = lse[i0], l1 = lse[i1];
      float mm = fmaxf(l0,l1);
      float w0 = expf(l0-mm), w1 = expf(l1-mm);
      float inv = 1.0f/(w0+w1);
      w0*=inv; w1*=inv;
      const unsigned short* p0 = o_r16 + i0*128 + dbase;
      const unsigned short* p1 = o_r16 + i1*128 + dbase;
      uint4 u0 = *(const uint4*)p0;
      uint4 u1 = *(const uint4*)p1;
      float f[8];
      #pragma unroll
      for (int j=0;j<4;j++){
        unsigned av = ((const unsigned*)&u0)[j];
        unsigned cv = ((const unsigned*)&u1)[j];
        f[2*j]   = w0*bf2f((unsigned short)(av & 0xffff)) + w1*bf2f((unsigned short)(cv & 0xffff));
        f[2*j+1] = w0*bf2f((unsigned short)(av >> 16))    + w1*bf2f((unsigned short)(cv >> 16));
      }
      uint4 ua = { bpack2(f[0],f[1]), bpack2(f[2],f[3]), bpack2(f[4],f[5]), bpack2(f[6],f[7]) };
      *(uint4*)&a_sh[row*BST + scol] = ua;
      const float4 g0 = *(const float4*)(W + (size_t)(n0+row)*K + kt + scol);
      const float4 g1 = *(const float4*)(W + (size_t)(n0+row)*K + kt + scol + 4);
      uint4 uw = { bpack2(g0.x,g0.y), bpack2(g0.z,g0.w), bpack2(g1.x,g1.y), bpack2(g1.z,g1.w) };
      *(uint4*)&w_sh[row*BST + scol] = uw;
    }
    __syncthreads();
    #pragma unroll
    for (int ks = 0; ks < 64; ks += 32){
      short8 af[4], bw[4];
      #pragma unroll
      for (int i=0;i<4;i++) af[i] = *(const short8*)&a_sh[(mw + i*16 + lr)*BST + ks + lg*8];
      #pragma unroll
      for (int j=0;j<4;j++) bw[j] = *(const short8*)&w_sh[(nw + j*16 + lr)*BST + ks + lg*8];
      #pragma unroll
      for (int i=0;i<4;i++)
        #pragma unroll
        for (int j=0;j<4;j++)
          acc[i][j] = __builtin_amdgcn_mfma_f32_16x16x32_bf16(af[i], bw[j], acc[i][j], 0, 0, 0);
    }
  }
  #pragma unroll
  for (int j=0;j<4;j++){
    int col = n0 + nw + j*16 + lr;
    float bs = bias[col];
    #pragma unroll
    for (int i=0;i<4;i++){
      int rbase = m0 + mw + i*16 + lg*4;
      #pragma unroll
      for (int r=0;r<4;r++)
        C[(size_t)(rbase+r)*ldc + col] = acc[i][j][r] + bs;
    }
  }
}

// ---------- per-row norm over E (q stride now 1024) ----------
__global__ __launch_bounds__(256) void invnorm_kernel(const float* __restrict__ q32,
                                                      float* __restrict__ invn,
                                                      float* __restrict__ nrm)
{
  int row = blockIdx.x;
  int t = threadIdx.x;
  float4 v = *(const float4*)(q32 + (size_t)row*1024 + t*4);
  float ss = v.x*v.x + v.y*v.y + v.z*v.z + v.w*v.w;
  #pragma unroll
  for (int off=32; off; off>>=1) ss += __shfl_down(ss, off);
  __shared__ float part[4];
  if ((t & 63)==0) part[t>>6] = ss;
  __syncthreads();
  if (t==0){
    float n = sqrtf(part[0]+part[1]+part[2]+part[3]);
    nrm[row]  = n;
    invn[row] = 1.0f/n;
  }
}

// ---------- fp32 hash path, reference-order mimicry (R5 pass; DO NOT TOUCH math) ----------
__global__ __launch_bounds__(256) void hash32_kernel(
    const float* __restrict__ q32, const float* __restrict__ nrm,
    const float* __restrict__ hw, int* __restrict__ hashes)
{
  int idx = blockIdx.x*256 + threadIdx.x;
  int s = idx & (S_LEN-1);
  int h = (idx >> 12) & 7;
  int r = (idx >> 15) & 1;
  int b = idx >> 16;
  const float* qr = q32 + (size_t)(s*B_SZ + b)*1024 + h*D_HEAD;
  const float  n  = nrm[s*B_SZ + b];
  const float* wp = hw + (size_t)(r*H_HEADS + h)*D_HEAD*8;
  float lin[8];
  #pragma unroll
  for (int m=0;m<8;m++) lin[m]=0.f;
  for (int d=0; d<D_HEAD; d++){
    float kd = qr[d] / n;
    #pragma unroll
    for (int m=0;m<8;m++) lin[m] = fmaf(kd, wp[d*8+m], lin[m]);
  }
  float best = lin[0]; int bi = 0;
  #pragma unroll
  for (int m=1;m<8;m++) if (lin[m] > best){ best=lin[m]; bi=m; }
  #pragma unroll
  for (int m=0;m<8;m++) if (-lin[m] > best){ best=-lin[m]; bi=8+m; }
  hashes[idx] = bi;
}

// ---------- stable counting sort by bucket, per (b,r,h) ----------
__global__ __launch_bounds__(256) void sort_kernel(const int* __restrict__ hashes,
                                                   int* __restrict__ sidx,
                                                   unsigned short* __restrict__ hs_pack)
{
  __shared__ unsigned char bucket_s[S_LEN];
  __shared__ int counts[16][257];
  __shared__ int bbase[16];
  int t = threadIdx.x;
  size_t base = (size_t)blockIdx.x * S_LEN;
  for (int e=0;e<16;e++) bucket_s[t + e*256] = (unsigned char)hashes[base + t + e*256];
  #pragma unroll
  for (int u=0;u<16;u++) counts[u][t]=0;
  if (t<16) counts[t][256]=0;
  __syncthreads();
  int s0 = t*16;
  for (int e=0;e<16;e++){ int u = bucket_s[s0+e]; counts[u][t]++; }
  __syncthreads();
  if (t < 16){
    int run=0;
    for (int tt=0; tt<256; tt++){ int c = counts[t][tt]; counts[t][tt]=run; run+=c; }
    counts[t][256]=run;
  }
  __syncthreads();
  if (t==0){
    int run=0;
    for (int u=0;u<16;u++){ bbase[u]=run; run += counts[u][256]; }
  }
  __syncthreads();
  for (int e=0;e<16;e++){
    int s = s0+e; int u = bucket_s[s];
    int pos = bbase[u] + counts[u][t]; counts[u][t]++;
    sidx[base+pos] = s;
    hs_pack[base+pos] = (unsigned short)(s | (u<<12));
  }
}

// ---------- gather: sorted bf16 K-hat rows + transposed V ----------
// ksort[brh][pos][d]  = q[token][h,d] * invn[token]   (bf16, from fp32 q)
// vsortT[brh][d][pos] = v[token][h,d]                 (bf16 copy from v16)
#define GST 136
__global__ __launch_bounds__(256) void gather_kernel(
    const float* __restrict__ q32, const unsigned short* __restrict__ v16,
    const float* __restrict__ invn, const int* __restrict__ sidx,
    unsigned short* __restrict__ ksort, unsigned short* __restrict__ vsortT)
{
  __shared__ int tok_s[256];
  __shared__ float sc_s[256];
  __shared__ unsigned short v_sub[64*GST];
  const int t = threadIdx.x;
  const int brh = blockIdx.x >> 4, pc = blockIdx.x & 15;
  const int b = brh >> 4;
  const int h = brh & 7;
  const size_t base_s = (size_t)brh * S_LEN;
  const int pos0 = pc * 256;
  {
    int tok = sidx[base_s + pos0 + t];
    tok_s[t] = tok;
    sc_s[t] = invn[tok*B_SZ + b];
  }
  __syncthreads();
  // ksort: coalesced row-major bf16
  #pragma unroll 4
  for (int i=0;i<16;i++){
    int slot = i*256 + t;
    int pos = slot >> 4, g = slot & 15;
    int tok = tok_s[pos]; float sc = sc_s[pos];
    const float* src = q32 + ((size_t)tok*B_SZ + b)*1024 + h*D_HEAD + g*8;
    float4 f0 = *(const float4*)src, f1 = *(const float4*)(src+4);
    uint4 u = { bpack2(f0.x*sc, f0.y*sc), bpack2(f0.z*sc, f0.w*sc),
                bpack2(f1.x*sc, f1.y*sc), bpack2(f1.z*sc, f1.w*sc) };
    *(uint4*)&ksort[(base_s + pos0 + pos)*128 + g*8] = u;
  }
  // vsortT: 4 sub-tiles of 64 pos, LDS transpose (v already bf16 -> raw copy)
  for (int sub=0; sub<4; sub++){
    __syncthreads();
    #pragma unroll
    for (int i=0;i<4;i++){
      int slot = i*256 + t;
      int pr = slot >> 4, g = slot & 15;
      int tok = tok_s[sub*64 + pr];
      uint4 u = *(const uint4*)(v16 + ((size_t)tok*B_SZ + b)*1024 + h*D_HEAD + g*8);
      *(uint4*)&v_sub[pr*GST + g*8] = u;
    }
    __syncthreads();
    #pragma unroll
    for (int i=0;i<8;i++){
      int oslot = i*256 + t;             // 2048 = 128 d x 16 pos-groups
      int d = oslot >> 4, p4 = (oslot & 15)*4;
      unsigned a0 = v_sub[(p4+0)*GST + d];
      unsigned a1 = v_sub[(p4+1)*GST + d];
      unsigned a2 = v_sub[(p4+2)*GST + d];
      unsigned a3 = v_sub[(p4+3)*GST + d];
      uint2 o = { a0 | (a1<<16), a2 | (a3<<16) };
      *(uint2*)&vsortT[(size_t)brh*524288 + (size_t)d*4096 + pos0 + sub*64 + p4] = o;
    }
  }
}

// ---------- MFMA chunked LSH attention (R15-exact; R17 prefetch reverted:
// +16 VGPR state across barriers crossed an occupancy step and regressed) ----------
#define KST 136
#define VST 72
#define PST 200
__device__ inline int swzg(int row, int g){ return (g ^ (row & 7)) << 3; }

__global__ __launch_bounds__(256) void attn_mfma_kernel(
    const unsigned short* __restrict__ ksort, const unsigned short* __restrict__ vsortT,
    const float* __restrict__ nrm, const unsigned short* __restrict__ hs_pack,
    unsigned short* __restrict__ o_r16, float* __restrict__ lse_g)
{
  __shared__ unsigned short kv_un[128*VST];          // 9216 u16: K chunk (64x136) or V^T chunk (128x72)
  __shared__ unsigned short p_sh[64*PST];
  __shared__ __align__(16) unsigned short pack_s[S_LEN];
  __shared__ float srow_s[64];

  const int t = threadIdx.x;
  const int bid = blockIdx.x;
  const int nc = bid & 63;
  const int brh = bid >> 6;
  const int b = brh >> 4;
  const size_t base_s = (size_t)brh * S_LEN;

  {
    const uint4* src = (const uint4*)(hs_pack + base_s);
    uint4* dst = (uint4*)pack_s;
    dst[t]       = src[t];
    dst[256 + t] = src[256 + t];
  }
  __syncthreads();
  if (t < 64){
    int tok = pack_s[nc*64 + t] & 0xfff;
    srow_s[t] = SCALE_F * nrm[tok*B_SZ + b];
  }

  const int lane = t & 63, wid = t >> 6;
  const int mw = wid * 16;                 // wave's 16 query rows
  const int lr = lane & 15, lg = lane >> 4;

  f32x4 acc[12];
  #pragma unroll
  for (int i=0;i<12;i++) acc[i] = (f32x4){0.f,0.f,0.f,0.f};
  short8 aq[4];

  // ---- QK^T: window chunks, w=1 first (supplies Q fragments) ----
  const int worder[3] = {1, 0, 2};
  #pragma unroll
  for (int wi=0; wi<3; wi++){
    int w = worder[wi];
    int cwch = (nc + w + 63) & 63;
    __syncthreads();                       // also covers srow_s on first iter
    #pragma unroll
    for (int i=0;i<4;i++){
      int slot = i*256 + t;
      int row = slot >> 4, g = slot & 15;
      uint4 u = *(const uint4*)&ksort[(base_s + cwch*64 + row)*128 + g*8];
      *(uint4*)&kv_un[row*KST + swzg(row, g)] = u;
    }
    __syncthreads();
    if (wi==0){
      #pragma unroll
      for (int ks=0; ks<4; ks++)
        aq[ks] = *(const short8*)&kv_un[(mw+lr)*KST + swzg(mw+lr, ks*4+lg)];
    }
    #pragma unroll
    for (int ks=0; ks<4; ks++){
      #pragma unroll
      for (int k4=0; k4<4; k4++){
        short8 bk = *(const short8*)&kv_un[(k4*16+lr)*KST + swzg(k4*16+lr, ks*4+lg)];
        acc[w*4+k4] = __builtin_amdgcn_mfma_f32_16x16x32_bf16(aq[ks], bk, acc[w*4+k4], 0,0,0);
      }
    }
  }

  // ---- scale + masks + softmax (C-layout: col=lr, rows mw+lg*4+r) ----
  unsigned pq[4]; float sr[4]; int c_[4]; float linv[4];
  #pragma unroll
  for (int r=0;r<4;r++){
    c_[r] = mw + lg*4 + r;
    pq[r] = pack_s[nc*64 + c_[r]];
    sr[r] = srow_s[c_[r]];
  }
  #pragma unroll
  for (int ti=0; ti<12; ti++){
    int w = ti >> 2, k4 = ti & 3;
    #pragma unroll
    for (int r=0;r<4;r++){
      int mc = (c_[r] + w + 63) & 63;
      unsigned e = pack_s[mc*64 + k4*16 + lr];
      float s = acc[ti][r] * sr[r];
      s = ((e>>12) == (pq[r]>>12)) ? s : NEG_F;
      if ((e & 0xfffu) == (pq[r] & 0xfffu)) s = NEG_SELF_F;
      acc[ti][r] = s;
    }
  }
  #pragma unroll
  for (int r=0;r<4;r++){
    float m = acc[0][r];
    #pragma unroll
    for (int ti=1; ti<12; ti++) m = fmaxf(m, acc[ti][r]);
    #pragma unroll
    for (int off=1; off<16; off<<=1) m = fmaxf(m, __shfl_xor(m, off));
    float l = 0.f;
    #pragma unroll
    for (int ti=0; ti<12; ti++){
      float p = __expf(acc[ti][r] - m);
      l += p;
      int wpos = (ti>>2)*64 + (ti&3)*16 + lr;
      p_sh[c_[r]*PST + (((wpos>>3) ^ (c_[r]&7))<<3) + (wpos&7)] = (unsigned short)bfr(p);
    }
    #pragma unroll
    for (int off=1; off<16; off<<=1) l += __shfl_xor(l, off);
    linv[r] = 1.0f / l;
    if (lr == 0) lse_g[base_s + (pq[r] & 0xfffu)] = m + logf(l);
  }

  // ---- PV ----
  f32x4 oacc[8];
  #pragma unroll
  for (int i=0;i<8;i++) oacc[i] = (f32x4){0.f,0.f,0.f,0.f};
  for (int w=0; w<3; w++){
    int cwch = (nc + w + 63) & 63;
    __syncthreads();                       // p_sh written; kv_un free
    #pragma unroll
    for (int i=0;i<4;i++){
      int slot = i*256 + t;                // 1024 = 128 d x 8 key-groups
      int d = slot >> 3, kg = slot & 7;
      uint4 u = *(const uint4*)&vsortT[(size_t)brh*524288 + (size_t)d*4096 + cwch*64 + kg*8];
      *(uint4*)&kv_un[d*VST + swzg(d, kg)] = u;
    }
    __syncthreads();
    short8 ap[2];
    #pragma unroll
    for (int ks=0; ks<2; ks++){
      int g = w*8 + ks*4 + lg;
      ap[ks] = *(const short8*)&p_sh[(mw+lr)*PST + ((g ^ ((mw+lr)&7))<<3)];
    }
    #pragma unroll
    for (int ks=0; ks<2; ks++)
      #pragma unroll
      for (int dt=0; dt<8; dt++){
        short8 bv = *(const short8*)&kv_un[(dt*16+lr)*VST + swzg(dt*16+lr, ks*4+lg)];
        oacc[dt] = __builtin_amdgcn_mfma_f32_16x16x32_bf16(ap[ks], bv, oacc[dt], 0,0,0);
      }
  }

  // ---- epilogue: bf16 scatter by token ----
  #pragma unroll
  for (int r=0;r<4;r++){
    int tok = pq[r] & 0xfff;
    size_t ob = (base_s + tok) * 128;
    #pragma unroll
    for (int dt=0; dt<8; dt++)
      o_r16[ob + dt*16 + lr] = (unsigned short)bfr(oacc[dt][r] * linv[r]);
  }
}

// ---------- launch ----------
extern "C" void kernel_launch(void* const* d_in, const int* in_sizes, int n_in,
                              void* d_out, int out_size, void* d_ws, size_t ws_size,
                              hipStream_t stream)
{
  (void)in_sizes; (void)n_in; (void)out_size; (void)ws_size;
  const float* x  = (const float*)d_in[0];
  const float* wq = (const float*)d_in[1];
  const float* bq = (const float*)d_in[2];
  const float* wv = (const float*)d_in[3];
  const float* bv = (const float*)d_in[4];
  const float* wo = (const float*)d_in[5];
  const float* bo = (const float*)d_in[6];
  const float* hw = (const float*)d_in[7];
  float* out = (float*)d_out;

  float* ws    = (float*)d_ws;
  // layout (float offsets):
  float* q32   = ws;                                           // [8192][1024] fp32 q (32MB)
  unsigned short* v16 = (unsigned short*)(ws + 8388608);       // [8192][1024] bf16 v (16MB)
  float* invn  = ws + 12582912;                                // [8192]
  float* nrm   = ws + 12591104;                                // [8192]
  int*   hashes= (int*)(ws + 12599296);                        // [B,R,H,S]
  int*   sidx  = (int*)(ws + 12730368);                        // [B,R,H,S]
  float* lse   = ws + 12861440;                                // [B,R,H,S]
  unsigned short* o_r16   = (unsigned short*)(ws + 12992512);  // [32][4096][128] bf16 (33.5MB, written at attn)
  unsigned short* x16     = (unsigned short*)(ws + 12992512);  // overlays o_r16 front 16MB (dead before attn)
  unsigned short* wv16    = (unsigned short*)(ws + 17186816);  // overlays o_r16 next 2MB (dead before attn)
  unsigned short* ksort   = (unsigned short*)(ws + 21381120);  // [32][4096][128] bf16
  unsigned short* vsortT  = (unsigned short*)(ws + 29769728);  // [32][128][4096] bf16
  unsigned short* hs_pack = (unsigned short*)(ws + 38158336);  // [B,R,H,S] packed

  cvt_bf16_kernel<<<dim3(4096), 256, 0, stream>>>(x,  x16,  1048576);   // 8192*1024/8
  cvt_bf16_kernel<<<dim3(512),  256, 0, stream>>>(wv, wv16, 131072);    // 1024*1024/8
  gemm_f32_kernel<<<dim3(8,64), 256, 0, stream>>>(x, wq, bq, q32, 1024, 1024, 1024);
  gemm_bf16v_kernel<<<dim3(8,64), 256, 0, stream>>>(x16, wv16, bv, v16, 1024, 1024);
  invnorm_kernel<<<dim3(8192), 256, 0, stream>>>(q32, invn, nrm);
  hash32_kernel<<<dim3(512), 256, 0, stream>>>(q32, nrm, hw, hashes);
  sort_kernel<<<dim3(32), 256, 0, stream>>>(hashes, sidx, hs_pack);
  gather_kernel<<<dim3(512), 256, 0, stream>>>(q32, v16, invn, sidx, ksort, vsortT);
  attn_mfma_kernel<<<dim3(2048), 256, 0, stream>>>(ksort, vsortT, nrm, hs_pack, o_r16, lse);
  gemm_out_kernel<<<dim3(8,64), 256, 0, stream>>>(o_r16, lse, wo, bo, out);
}